// Round 13
// baseline (252.216 us; speedup 1.0000x reference)
//
#include <hip/hip_runtime.h>
#include <stdint.h>

typedef unsigned short u16;
typedef _Float16 half8 __attribute__((ext_vector_type(8)));
typedef _Float16 half4 __attribute__((ext_vector_type(4)));
typedef _Float16 half2 __attribute__((ext_vector_type(2)));
typedef float f32x4 __attribute__((ext_vector_type(4)));

__device__ __forceinline__ u16 f2h(float f) {
    _Float16 h = (_Float16)f; u16 u; __builtin_memcpy(&u, &h, 2); return u;
}
__device__ __forceinline__ float h2f(u16 u) {
    _Float16 h; __builtin_memcpy(&h, &u, 2); return (float)h;
}

// ---------- DPP 16-lane sum (pure VALU) ----------
template<int CTRL>
__device__ __forceinline__ float dppf(float x) {
    return __builtin_bit_cast(float,
        __builtin_amdgcn_update_dpp(0, __builtin_bit_cast(int, x), CTRL, 0xF, 0xF, false));
}
__device__ __forceinline__ float sum16(float x) {
    x += dppf<0xB1>(x);
    x += dppf<0x4E>(x);
    x += dppf<0x124>(x);
    x += dppf<0x128>(x);
    return x;
}

// =======================================================================================
// Prep: all 8 weights -> fp16 transposed [N][K] (+scale fold), scaled biases, mask flag.
// =======================================================================================
__global__ __launch_bounds__(256) void prep_kernel(
    const float* __restrict__ W_qg, const float* __restrict__ W_kg,
    const float* __restrict__ W_qa, const float* __restrict__ W_ka,
    const float* __restrict__ W_v,  const float* __restrict__ W_o,
    const float* __restrict__ W_m1, const float* __restrict__ W_m2,
    u16* __restrict__ T_qg, u16* __restrict__ T_kg, u16* __restrict__ T_qa,
    u16* __restrict__ T_ka, u16* __restrict__ T_v,  u16* __restrict__ T_o,
    u16* __restrict__ T_m1, u16* __restrict__ T_m2,
    const float* __restrict__ scale_g, const float* __restrict__ scale_a,
    const float* __restrict__ b_kg, const float* __restrict__ b_ka,
    float* __restrict__ bkg_s, float* __restrict__ bka_s,
    const int* __restrict__ mask, int* __restrict__ mflag)
{
    const int z = blockIdx.z;
    const int tid = threadIdx.x;
    if (z == 8) {
        if (blockIdx.y != 0) return;
        if (blockIdx.x == 0) {
            __shared__ int f;
            if (tid == 0) f = 0;
            __syncthreads();
            int local = 0;
            for (int i = tid; i < 2112; i += 256) { int vv = mask[i]; if (vv & ~1) local = 1; }
            if (local) atomicOr(&f, 1);
            __syncthreads();
            if (tid == 0) *mflag = f;
        } else if (blockIdx.x == 1) {
            for (int j = tid; j < 512; j += 256) {
                bkg_s[j] = b_kg[j] * scale_g[j >> 6];
                bka_s[j] = b_ka[j] * scale_a[j >> 6];
            }
        }
        return;
    }
    const int K = (z == 5 || z == 7) ? 512 : 256;
    const int N = (z == 5 || z == 7) ? 256 : 512;
    const int k0 = blockIdx.x * 64, n0 = blockIdx.y * 64;
    if (k0 >= K || n0 >= N) return;
    const float* W = z==0?W_qg: z==1?W_kg: z==2?W_qa: z==3?W_ka: z==4?W_v: z==5?W_o: z==6?W_m1: W_m2;
    u16* D        = z==0?T_qg: z==1?T_kg: z==2?T_qa: z==3?T_ka: z==4?T_v: z==5?T_o: z==6?T_m1: T_m2;
    const float* scp = z==1 ? scale_g : z==3 ? scale_a : nullptr;

    __shared__ u16 T[64][80];
    const int cr = tid >> 4, cc = (tid & 15) * 4;
    const float sc = scp ? scp[(n0 + cc) >> 6] : 1.0f;
    #pragma unroll
    for (int i = 0; i < 4; ++i) {
        const int r = cr + i * 16;
        const float4 vv = *(const float4*)(W + (size_t)(k0 + r) * N + n0 + cc);
        T[cc + 0][r] = f2h(vv.x * sc);
        T[cc + 1][r] = f2h(vv.y * sc);
        T[cc + 2][r] = f2h(vv.z * sc);
        T[cc + 3][r] = f2h(vv.w * sc);
    }
    __syncthreads();
    const int nr = tid >> 2, part = (tid & 3) * 16;
    u16* drow = D + (size_t)(n0 + nr) * K + k0 + part;
    *(half8*)(drow)     = *(const half8*)&T[nr][part];
    *(half8*)(drow + 8) = *(const half8*)&T[nr][part + 8];
}

// =======================================================================================
// All 5 projections in ONE dispatch. grid (496, 2). W slice LDS-staged per k-step.
// (r9 exact version — best-measured total.)
// =======================================================================================
__global__ __launch_bounds__(256, 4) void proj_all(
    const float* __restrict__ k_g, const float* __restrict__ k_a,
    const float* __restrict__ v,   const float* __restrict__ q_g,
    const float* __restrict__ q_a,
    const u16* __restrict__ T_kg, const u16* __restrict__ T_ka,
    const u16* __restrict__ T_v,  const u16* __restrict__ T_qg,
    const u16* __restrict__ T_qa,
    const float* __restrict__ bkg_s, const float* __restrict__ bka_s,
    const float* __restrict__ b_v,   const float* __restrict__ b_qg,
    const float* __restrict__ b_qa,
    u16* __restrict__ qcat, u16* __restrict__ kcat, u16* __restrict__ vt)
{
    __shared__ u16 Ws[256 * 36];

    int bx = blockIdx.x;
    int mode, M;
    const float* X; const u16* Wt; const float* bias; u16* out;
    if (bx < 132)      { mode = 2; M = 8448; X = k_g; Wt = T_kg; bias = bkg_s; out = kcat; }
    else if (bx < 264) { mode = 3; M = 8448; X = k_a; Wt = T_ka; bias = bka_s; out = kcat; bx -= 132; }
    else if (bx < 396) { mode = 4; M = 8448; X = v;   Wt = T_v;  bias = b_v;   out = vt;   bx -= 264; }
    else if (bx < 481) { mode = 0; M = 5400; X = q_g; Wt = T_qg; bias = b_qg;  out = qcat; bx -= 396; }
    else               { mode = 1; M = 900;  X = q_a; Wt = T_qa; bias = b_qa;  out = qcat; bx -= 481; }
    const int rows_per_n = (mode == 0) ? 900 : 1408;

    const int tid = threadIdx.x;
    const int w = tid >> 6, lane = tid & 63;
    const int l15 = lane & 15, quad = lane >> 4;
    const int m0 = bx * 64;
    const int nbase = blockIdx.y * 256;
    const int row = m0 + w * 16 + l15;

    const float* xrow = X + (size_t)(row < M ? row : 0) * 256 + quad * 8;
    const u16* wcol = Wt + ((size_t)(nbase + tid) << 8);

    f32x4 o[4][4];
    #pragma unroll
    for (int nt = 0; nt < 4; ++nt)
        #pragma unroll
        for (int t = 0; t < 4; ++t) { o[nt][t][0]=0.f; o[nt][t][1]=0.f; o[nt][t][2]=0.f; o[nt][t][3]=0.f; }

    for (int k0 = 0; k0 < 8; ++k0) {
        {
            const uint4 w0 = *(const uint4*)(wcol + k0 * 32 + 0);
            const uint4 w1 = *(const uint4*)(wcol + k0 * 32 + 8);
            const uint4 w2 = *(const uint4*)(wcol + k0 * 32 + 16);
            const uint4 w3 = *(const uint4*)(wcol + k0 * 32 + 24);
            *(uint4*)&Ws[tid * 36 + 0]  = w0;
            *(uint4*)&Ws[tid * 36 + 8]  = w1;
            *(uint4*)&Ws[tid * 36 + 16] = w2;
            *(uint4*)&Ws[tid * 36 + 24] = w3;
        }
        __syncthreads();

        const float4 a0 = *(const float4*)(xrow + k0 * 32);
        const float4 a1 = *(const float4*)(xrow + k0 * 32 + 4);
        half8 af;
        af[0]=(_Float16)a0.x; af[1]=(_Float16)a0.y; af[2]=(_Float16)a0.z; af[3]=(_Float16)a0.w;
        af[4]=(_Float16)a1.x; af[5]=(_Float16)a1.y; af[6]=(_Float16)a1.z; af[7]=(_Float16)a1.w;

        #pragma unroll
        for (int nt = 0; nt < 4; ++nt)
            #pragma unroll
            for (int t = 0; t < 4; ++t) {
                const half8 bf = *(const half8*)&Ws[(nt * 64 + t * 16 + l15) * 36 + quad * 8];
                o[nt][t] = __builtin_amdgcn_mfma_f32_16x16x32_f16(af, bf, o[nt][t], 0, 0, 0);
            }
        __syncthreads();
    }

    #pragma unroll
    for (int nt = 0; nt < 4; ++nt) {
        const int n0 = nbase + nt * 64;
        const int hh = n0 >> 6;
        float bj[4];
        #pragma unroll
        for (int t = 0; t < 4; ++t) bj[t] = bias[n0 + t * 16 + l15];

        if (mode == 4) {
            const int gr0 = m0 + w * 16 + quad * 4;
            if (gr0 < M) {
                const int nI = gr0 / rows_per_n;
                const int rr = gr0 - nI * rows_per_n;
                u16* vb = out + (size_t)(hh * 6 + nI) * 64 * 1408;
                #pragma unroll
                for (int t = 0; t < 4; ++t) {
                    const int d = t * 16 + l15;
                    ushort4 pk;
                    pk.x = f2h(o[nt][t][0] + bj[t]);
                    pk.y = f2h(o[nt][t][1] + bj[t]);
                    pk.z = f2h(o[nt][t][2] + bj[t]);
                    pk.w = f2h(o[nt][t][3] + bj[t]);
                    *(ushort4*)&vb[(size_t)d * 1408 + rr] = pk;
                }
            }
        } else if (mode == 1) {
            #pragma unroll
            for (int r = 0; r < 4; ++r) {
                const int gr = m0 + w * 16 + quad * 4 + r;
                if (gr < M) {
                    for (int nb = 0; nb < 6; ++nb) {
                        u16* qb = out + (((size_t)(hh * 6 + nb) * 900 + gr) << 7) + 64;
                        #pragma unroll
                        for (int t = 0; t < 4; ++t)
                            qb[t * 16 + l15] = f2h(o[nt][t][r] + bj[t]);
                    }
                }
            }
        } else {
            const size_t kdim = (mode == 0) ? 900 : 1408;
            const int doff = (mode == 3) ? 64 : 0;
            #pragma unroll
            for (int r = 0; r < 4; ++r) {
                const int gr = m0 + w * 16 + quad * 4 + r;
                if (gr < M) {
                    const int nI = gr / rows_per_n;
                    const int rr = gr - nI * rows_per_n;
                    u16* ob = out + (((size_t)(hh * 6 + nI) * kdim + rr) << 7) + doff;
                    #pragma unroll
                    for (int t = 0; t < 4; ++t)
                        ob[t * 16 + l15] = f2h(o[nt][t][r] + bj[t]);
                }
            }
        }
    }
}

// =======================================================================================
// MFMA flash attention — r12 measured-best: 512-thread / 8-wave / 128-q-row blocks.
// (52.4 µs, VGPR 56, grid 768.) Unchanged this round.
// =======================================================================================
__global__ __launch_bounds__(512, 4) void attn_kernel(
    const u16* __restrict__ qcat, const u16* __restrict__ kcat,
    const u16* __restrict__ vt, const void* __restrict__ maskp,
    const int* __restrict__ mflag,
    u16* __restrict__ Opart, float* __restrict__ lpart)
{
    __shared__ __align__(16) u16 Ks[64 * 136];   // 17.4 KB
    __shared__ __align__(16) u16 Vs[64 * 72];    //  9.2 KB
    __shared__ __align__(16) u16 Ps[8][1216];    // 19.4 KB, row*72 + (row>>2)*16 + col
    __shared__ float Mb[64];

    const int flat = blockIdx.x;                 // 768 = 48 hn x 8 qt x 2 sp
    const int hn_i = (flat & 7) + 8 * ((flat >> 3) % 6);
    const int rest = flat / 48;                  // 0..15
    const int qt = rest & 7;
    const int sp = rest >> 3;
    const int n = hn_i - (hn_i / 6) * 6;

    const int q0 = qt * 128;
    const int tid = threadIdx.x;
    const int w = tid >> 6, lane = tid & 63;     // w 0..7
    const int l15 = lane & 15, quad = lane >> 4;
    const bool m8 = (*mflag != 0);
    const size_t hn = (size_t)hn_i;

    const u16* kbase = kcat + ((hn * 1408) << 7);
    const u16* vbase = vt + hn * 64 * 1408;
    const unsigned char* mB = (const unsigned char*)maskp;
    const int* mI = (const int*)maskp;
    const int mko = n * 1408;

    const int krow_s = tid >> 4;                 // 0..31 (two K rows per thread)
    const int kcol_s = (tid & 15) * 8;
    const int vrow_s = tid >> 3;                 // 0..63 (one V row per thread)
    const int vcol_s = (tid & 7) * 8;

    half8 qf[4];
    {
        const int gq = q0 + w * 16 + l15;
        if (gq < 900) {
            const u16* qrow = qcat + ((hn * 900 + gq) << 7) + quad * 8;
            #pragma unroll
            for (int k0 = 0; k0 < 4; ++k0)
                qf[k0] = *(const half8*)(qrow + k0 * 32);
        } else {
            #pragma unroll
            for (int k0 = 0; k0 < 4; ++k0)
                #pragma unroll
                for (int j = 0; j < 8; ++j) qf[k0][j] = (_Float16)0.0f;
        }
    }

    // ones-column B fragment: B[k][0]=1 for all k -> D[:,0] = row sums of A
    half8 onesb;
    {
        const _Float16 ov = (l15 == 0) ? (_Float16)1.0f : (_Float16)0.0f;
        #pragma unroll
        for (int j = 0; j < 8; ++j) onesb[j] = ov;
    }

    f32x4 o[4];
    f32x4 l16;
    #pragma unroll
    for (int t = 0; t < 4; ++t) { o[t][0]=0.f; o[t][1]=0.f; o[t][2]=0.f; o[t][3]=0.f; }
    l16[0]=0.f; l16[1]=0.f; l16[2]=0.f; l16[3]=0.f;

    // ---- prefetch chunk 0 into registers ----
    uint4 kA, kB, vA;
    float mreg = 0.0f;
    {
        const int k0c = sp * 11 * 64;
        kA = *(const uint4*)(kbase + ((size_t)(k0c +  0 + krow_s) << 7) + kcol_s);
        kB = *(const uint4*)(kbase + ((size_t)(k0c + 32 + krow_s) << 7) + kcol_s);
        vA = *(const uint4*)(vbase + (size_t)(vrow_s) * 1408 + k0c + vcol_s);
        if (tid < 64) {
            const int ki = mko + k0c + tid;
            const int mv = m8 ? (int)mB[ki] : mI[ki];
            mreg = mv ? -1e30f : 0.0f;
        }
    }

    for (int cc = 0; cc < 11; ++cc) {
        // ---- stage prefetched registers to LDS ----
        *(uint4*)&Ks[( 0 + krow_s) * 136 + kcol_s] = kA;
        *(uint4*)&Ks[(32 + krow_s) * 136 + kcol_s] = kB;
        *(uint4*)&Vs[vrow_s * 72 + vcol_s] = vA;
        if (tid < 64) Mb[tid] = mreg;
        __syncthreads();

        // ---- issue next chunk's global loads (in flight under compute) ----
        if (cc < 10) {
            const int k0n = (sp * 11 + cc + 1) * 64;
            kA = *(const uint4*)(kbase + ((size_t)(k0n +  0 + krow_s) << 7) + kcol_s);
            kB = *(const uint4*)(kbase + ((size_t)(k0n + 32 + krow_s) << 7) + kcol_s);
            vA = *(const uint4*)(vbase + (size_t)(vrow_s) * 1408 + k0n + vcol_s);
            if (tid < 64) {
                const int ki = mko + k0n + tid;
                const int mv = m8 ? (int)mB[ki] : mI[ki];
                mreg = mv ? -1e30f : 0.0f;
            }
        }

        // ---- QK^T: accumulator seeded with mask bias ----
        f32x4 s[4];
        #pragma unroll
        for (int t = 0; t < 4; ++t) {
            const float mbv = Mb[t * 16 + l15];
            s[t][0]=mbv; s[t][1]=mbv; s[t][2]=mbv; s[t][3]=mbv;
        }
        #pragma unroll
        for (int k0 = 0; k0 < 4; ++k0)
            #pragma unroll
            for (int t = 0; t < 4; ++t) {
                const half8 kf = *(const half8*)&Ks[(t * 16 + l15) * 136 + k0 * 32 + quad * 8];
                s[t] = __builtin_amdgcn_mfma_f32_16x16x32_f16(qf[k0], kf, s[t], 0, 0, 0);
            }

        // ---- softmax-lite: plain exp, P -> LDS (skewed layout) ----
        #pragma unroll
        for (int r = 0; r < 4; ++r) {
            const float p0 = __expf(s[0][r]);
            const float p1 = __expf(s[1][r]);
            const float p2 = __expf(s[2][r]);
            const float p3 = __expf(s[3][r]);
            u16* pr = &Ps[w][(quad * 4 + r) * 72 + quad * 16 + l15];
            pr[0]  = f2h(p0);
            pr[16] = f2h(p1);
            pr[32] = f2h(p2);
            pr[48] = f2h(p3);
        }

        const u16* prow = &Ps[w][l15 * 72 + (l15 >> 2) * 16 + quad * 8];
        const half8 pa0 = *(const half8*)(prow);
        const half8 pa1 = *(const half8*)(prow + 32);

        // row sums via ones-column MFMA (accumulated across all chunks)
        l16 = __builtin_amdgcn_mfma_f32_16x16x32_f16(pa0, onesb, l16, 0, 0, 0);
        l16 = __builtin_amdgcn_mfma_f32_16x16x32_f16(pa1, onesb, l16, 0, 0, 0);

        #pragma unroll
        for (int t = 0; t < 4; ++t) {
            const half8 v0 = *(const half8*)&Vs[(t * 16 + l15) * 72 + quad * 8];
            const half8 v1 = *(const half8*)&Vs[(t * 16 + l15) * 72 + 32 + quad * 8];
            o[t] = __builtin_amdgcn_mfma_f32_16x16x32_f16(pa0, v0, o[t], 0, 0, 0);
            o[t] = __builtin_amdgcn_mfma_f32_16x16x32_f16(pa1, v1, o[t], 0, 0, 0);
        }
        __syncthreads();
    }

    const int p = sp * 48 + hn_i;
    #pragma unroll
    for (int r = 0; r < 4; ++r) {
        const int gq = q0 + w * 16 + quad * 4 + r;
        if (gq < 900) {
            u16* db = Opart + ((size_t)p * 900 + gq) * 64 + l15;
            db[0]  = f2h(o[0][r]);
            db[16] = f2h(o[1][r]);
            db[32] = f2h(o[2][r]);
            db[48] = f2h(o[3][r]);
            if (l15 == 0) lpart[p * 900 + gq] = l16[r];
        }
    }
}

// =======================================================================================
// Fused epilogue megakernel — ROUND 13: 2 rows/block (grid 450). Halves the per-block
// latency chain (prologue merge + the serial phase fragment-load chains) at the cost of
// 2x weight L2 re-read (~+5 µs at 34 TB/s). MFMA rows 2..15 are garbage-but-finite
// (A16 duplicated via l15&1); stores guarded rl<2.
// =======================================================================================
__global__ __launch_bounds__(256) void epi_mega(
    const u16* __restrict__ Opart, const float* __restrict__ lpart,
    const u16* __restrict__ T_o,
    const u16* __restrict__ T_m1, const u16* __restrict__ T_m2,
    const float* __restrict__ b_o, const float* __restrict__ q_a,
    const float* __restrict__ ln1_g, const float* __restrict__ ln1_b,
    const float* __restrict__ b_m1, const float* __restrict__ b_m2,
    const float* __restrict__ ln2_g, const float* __restrict__ ln2_b,
    float* __restrict__ outf)
{
    __shared__ u16 A16[2][520];       // 2.1 KB combined attention rows
    __shared__ u16 Z1[16][264];       // 8.4 KB
    __shared__ u16 H[16][520];        // 16.6 KB
    __shared__ float Ssum[4][16];
    __shared__ float Ssq[4][16];

    const int tid = threadIdx.x;
    const int w = tid >> 6, lane = tid & 63;
    const int l15 = lane & 15, quad = lane >> 4;
    const int m0 = blockIdx.x * 2;

    // ================= Prologue: merge 12 partials for this block's 2 rows ============
    {
        const int r = tid >> 7;           // 0..1
        const int cg = tid & 127;         // col-group (4 cols each)
        const int c4 = cg * 4;
        const int hh = cg >> 4;           // head (16 cgs per 64-col head)
        const int d4 = (cg & 15) * 4;     // d-offset within head
        const int q = m0 + r;             // 900 % 2 == 0 -> always < 900
        float l = 0.f;
        float a0 = 0.f, a1 = 0.f, a2 = 0.f, a3 = 0.f;
        #pragma unroll
        for (int s = 0; s < 12; ++s) {
            const int p = ((s & 1) ? 48 : 0) + hh * 6 + (s >> 1);
            l += lpart[p * 900 + q];
            const ushort4 t0 = *(const ushort4*)&Opart[((size_t)p * 900 + q) * 64 + d4];
            a0 += h2f(t0.x); a1 += h2f(t0.y); a2 += h2f(t0.z); a3 += h2f(t0.w);
        }
        const float inv = 1.0f / fmaxf(l, 1e-30f);
        ushort4 o0;
        o0.x = f2h(a0 * inv); o0.y = f2h(a1 * inv); o0.z = f2h(a2 * inv); o0.w = f2h(a3 * inv);
        *(ushort4*)&A16[r][c4] = o0;
    }
    __syncthreads();

    // ================= Phase A: out-proj + LN1 =================
    {
        f32x4 acc[4];
        #pragma unroll
        for (int t = 0; t < 4; ++t) { acc[t][0]=0.f; acc[t][1]=0.f; acc[t][2]=0.f; acc[t][3]=0.f; }

        #pragma unroll
        for (int k0 = 0; k0 < 16; ++k0) {
            const half8 af = *(const half8*)&A16[l15 & 1][k0 * 32 + quad * 8];
            #pragma unroll
            for (int t = 0; t < 4; ++t) {
                const int nn = w * 64 + t * 16 + l15;
                const half8 bf = *(const half8*)(T_o + (size_t)nn * 512 + k0 * 32 + quad * 8);
                acc[t] = __builtin_amdgcn_mfma_f32_16x16x32_f16(af, bf, acc[t], 0, 0, 0);
            }
        }

        float vals[4][4];
        #pragma unroll
        for (int r = 0; r < 4; ++r) {
            const int row = m0 + ((quad * 4 + r) & 1);   // valid data only in rows 0..1
            float s = 0.f, sq = 0.f;
            #pragma unroll
            for (int t = 0; t < 4; ++t) {
                const int col = w * 64 + t * 16 + l15;
                const float x = acc[t][r] + b_o[col] + q_a[(size_t)row * 256 + col];
                vals[r][t] = x; s += x; sq += x * x;
            }
            s = sum16(s); sq = sum16(sq);
            if (l15 == 0) { Ssum[w][quad * 4 + r] = s; Ssq[w][quad * 4 + r] = sq; }
        }
        __syncthreads();

        #pragma unroll
        for (int r = 0; r < 4; ++r) {
            const int rl = quad * 4 + r;
            const float st = Ssum[0][rl] + Ssum[1][rl] + Ssum[2][rl] + Ssum[3][rl];
            const float qt = Ssq[0][rl] + Ssq[1][rl] + Ssq[2][rl] + Ssq[3][rl];
            const float mean = st * (1.0f / 256.0f);
            const float var  = qt * (1.0f / 256.0f) - mean * mean;
            const float inv  = rsqrtf(var + 1e-5f);
            #pragma unroll
            for (int t = 0; t < 4; ++t) {
                const int col = w * 64 + t * 16 + l15;
                const float z = (vals[r][t] - mean) * inv * ln1_g[col] + ln1_b[col];
                Z1[rl][col] = f2h(z);
            }
        }
        __syncthreads();
    }

    // ================= Phase B: MLP1 + gelu =================
    {
        f32x4 acc[8];
        #pragma unroll
        for (int t = 0; t < 8; ++t) { acc[t][0]=0.f; acc[t][1]=0.f; acc[t][2]=0.f; acc[t][3]=0.f; }

        #pragma unroll
        for (int k0 = 0; k0 < 8; ++k0) {
            const half8 af = *(const half8*)&Z1[l15][k0 * 32 + quad * 8];
            #pragma unroll
            for (int t = 0; t < 8; ++t) {
                const int nn = w * 128 + t * 16 + l15;
                const half8 bf = *(const half8*)(T_m1 + (size_t)nn * 256 + k0 * 32 + quad * 8);
                acc[t] = __builtin_amdgcn_mfma_f32_16x16x32_f16(af, bf, acc[t], 0, 0, 0);
            }
        }

        #pragma unroll
        for (int r = 0; r < 4; ++r) {
            const int rl = quad * 4 + r;
            #pragma unroll
            for (int t = 0; t < 8; ++t) {
                const int col = w * 128 + t * 16 + l15;
                const float x = acc[t][r] + b_m1[col];
                H[rl][col] = f2h(0.5f * x * (1.0f + erff(x * 0.70710678118654752f)));
            }
        }
        __syncthreads();
    }

    // ================= Phase C: MLP2 + residual + LN2 =================
    {
        f32x4 acc[4];
        #pragma unroll
        for (int t = 0; t < 4; ++t) { acc[t][0]=0.f; acc[t][1]=0.f; acc[t][2]=0.f; acc[t][3]=0.f; }

        #pragma unroll
        for (int k0 = 0; k0 < 16; ++k0) {
            const half8 af = *(const half8*)&H[l15][k0 * 32 + quad * 8];
            #pragma unroll
            for (int t = 0; t < 4; ++t) {
                const int nn = w * 64 + t * 16 + l15;
                const half8 bf = *(const half8*)(T_m2 + (size_t)nn * 512 + k0 * 32 + quad * 8);
                acc[t] = __builtin_amdgcn_mfma_f32_16x16x32_f16(af, bf, acc[t], 0, 0, 0);
            }
        }

        float vals[4][4];
        #pragma unroll
        for (int r = 0; r < 4; ++r) {
            const int rl = quad * 4 + r;
            float s = 0.f, sq = 0.f;
            #pragma unroll
            for (int t = 0; t < 4; ++t) {
                const int col = w * 64 + t * 16 + l15;
                const float x = acc[t][r] + b_m2[col] + h2f(Z1[rl][col]);
                vals[r][t] = x; s += x; sq += x * x;
            }
            s = sum16(s); sq = sum16(sq);
            if (l15 == 0) { Ssum[w][rl] = s; Ssq[w][rl] = sq; }
        }
        __syncthreads();

        #pragma unroll
        for (int r = 0; r < 4; ++r) {
            const int rl = quad * 4 + r;
            const float st = Ssum[0][rl] + Ssum[1][rl] + Ssum[2][rl] + Ssum[3][rl];
            const float qt = Ssq[0][rl] + Ssq[1][rl] + Ssq[2][rl] + Ssq[3][rl];
            const float mean = st * (1.0f / 256.0f);
            const float var  = qt * (1.0f / 256.0f) - mean * mean;
            const float inv  = rsqrtf(var + 1e-5f);
            const int row = m0 + rl;
            if (rl < 2 && row < 900) {
                #pragma unroll
                for (int t = 0; t < 4; ++t) {
                    const int col = w * 64 + t * 16 + l15;
                    outf[(size_t)row * 256 + col] = (vals[r][t] - mean) * inv * ln2_g[col] + ln2_b[col];
                }
            }
        }
    }
}

extern "C" void kernel_launch(void* const* d_in, const int* in_sizes, int n_in,
                              void* d_out, int out_size, void* d_ws, size_t ws_size,
                              hipStream_t stream)
{
    const float* k_g  = (const float*)d_in[0];
    const float* q_g  = (const float*)d_in[1];
    const float* k_a  = (const float*)d_in[2];
    const float* q_a  = (const float*)d_in[3];
    const float* v    = (const float*)d_in[4];
    const void*  mask = d_in[5];
    const float* W_qg = (const float*)d_in[6];
    const float* b_qg = (const float*)d_in[7];
    const float* W_kg = (const float*)d_in[8];
    const float* b_kg = (const float*)d_in[9];
    const float* W_qa = (const float*)d_in[10];
    const float* b_qa = (const float*)d_in[11];
    const float* W_ka = (const float*)d_in[12];
    const float* b_ka = (const float*)d_in[13];
    const float* W_v  = (const float*)d_in[14];
    const float* b_v  = (const float*)d_in[15];
    const float* W_o  = (const float*)d_in[16];
    const float* b_o  = (const float*)d_in[17];
    const float* ln1_g = (const float*)d_in[18];
    const float* ln1_b = (const float*)d_in[19];
    const float* W_m1 = (const float*)d_in[20];
    const float* b_m1 = (const float*)d_in[21];
    const float* W_m2 = (const float*)d_in[22];
    const float* b_m2 = (const float*)d_in[23];
    const float* ln2_g = (const float*)d_in[24];
    const float* ln2_b = (const float*)d_in[25];
    const float* scale_g = (const float*)d_in[26];
    const float* scale_a = (const float*)d_in[27];

    char* ws = (char*)d_ws;
    size_t off = 0;
    auto alloc = [&](size_t bytes) -> void* {
        void* p = ws + off;
        off += (bytes + 255) & ~(size_t)255;
        return p;
    };
    u16*   qcat  = (u16*)  alloc((size_t)8 * 6 * 900  * 128 * 2);
    u16*   kcat  = (u16*)  alloc((size_t)8 * 6 * 1408 * 128 * 2);
    u16*   vt    = (u16*)  alloc((size_t)8 * 6 * 64 * 1408 * 2);
    u16*   Tw[8];
    for (int i = 0; i < 8; ++i) Tw[i] = (u16*)alloc((size_t)512 * 256 * 2);
    float* bkg_s = (float*)alloc((size_t)512 * 4);
    float* bka_s = (float*)alloc((size_t)512 * 4);
    int*   mflag = (int*)  alloc(256);
    u16*   Opart = (u16*)  alloc((size_t)96 * 900 * 64 * 2);
    float* lpart = (float*)alloc((size_t)96 * 900 * 4);

    prep_kernel<<<dim3(8, 8, 9), 256, 0, stream>>>(
        W_qg, W_kg, W_qa, W_ka, W_v, W_o, W_m1, W_m2,
        Tw[0], Tw[1], Tw[2], Tw[3], Tw[4], Tw[5], Tw[6], Tw[7],
        scale_g, scale_a, b_kg, b_ka, bkg_s, bka_s, (const int*)mask, mflag);

    proj_all<<<dim3(496, 2), 256, 0, stream>>>(
        k_g, k_a, v, q_g, q_a,
        Tw[1], Tw[3], Tw[4], Tw[0], Tw[2],
        bkg_s, bka_s, b_v, b_qg, b_qa,
        qcat, kcat, vt);

    attn_kernel<<<768, 512, 0, stream>>>(qcat, kcat, vt, mask, mflag, Opart, lpart);

    epi_mega<<<450, 256, 0, stream>>>(
        Opart, lpart, Tw[5], Tw[6], Tw[7],
        b_o, q_a, ln1_g, ln1_b, b_m1, b_m2, ln2_g, ln2_b,
        (float*)d_out);
}

// Round 14
// 243.861 us; speedup vs baseline: 1.0343x; 1.0343x over previous
//
#include <hip/hip_runtime.h>
#include <stdint.h>

typedef unsigned short u16;
typedef _Float16 half8 __attribute__((ext_vector_type(8)));
typedef _Float16 half4 __attribute__((ext_vector_type(4)));
typedef _Float16 half2 __attribute__((ext_vector_type(2)));
typedef float f32x4 __attribute__((ext_vector_type(4)));

__device__ __forceinline__ u16 f2h(float f) {
    _Float16 h = (_Float16)f; u16 u; __builtin_memcpy(&u, &h, 2); return u;
}
__device__ __forceinline__ float h2f(u16 u) {
    _Float16 h; __builtin_memcpy(&h, &u, 2); return (float)h;
}

// ---------- DPP 16-lane sum (pure VALU) ----------
template<int CTRL>
__device__ __forceinline__ float dppf(float x) {
    return __builtin_bit_cast(float,
        __builtin_amdgcn_update_dpp(0, __builtin_bit_cast(int, x), CTRL, 0xF, 0xF, false));
}
__device__ __forceinline__ float sum16(float x) {
    x += dppf<0xB1>(x);
    x += dppf<0x4E>(x);
    x += dppf<0x124>(x);
    x += dppf<0x128>(x);
    return x;
}

// =======================================================================================
// Prep: all 8 weights -> fp16 transposed [N][K] (+scale fold), scaled biases, mask flag.
// =======================================================================================
__global__ __launch_bounds__(256) void prep_kernel(
    const float* __restrict__ W_qg, const float* __restrict__ W_kg,
    const float* __restrict__ W_qa, const float* __restrict__ W_ka,
    const float* __restrict__ W_v,  const float* __restrict__ W_o,
    const float* __restrict__ W_m1, const float* __restrict__ W_m2,
    u16* __restrict__ T_qg, u16* __restrict__ T_kg, u16* __restrict__ T_qa,
    u16* __restrict__ T_ka, u16* __restrict__ T_v,  u16* __restrict__ T_o,
    u16* __restrict__ T_m1, u16* __restrict__ T_m2,
    const float* __restrict__ scale_g, const float* __restrict__ scale_a,
    const float* __restrict__ b_kg, const float* __restrict__ b_ka,
    float* __restrict__ bkg_s, float* __restrict__ bka_s,
    const int* __restrict__ mask, int* __restrict__ mflag)
{
    const int z = blockIdx.z;
    const int tid = threadIdx.x;
    if (z == 8) {
        if (blockIdx.y != 0) return;
        if (blockIdx.x == 0) {
            __shared__ int f;
            if (tid == 0) f = 0;
            __syncthreads();
            int local = 0;
            for (int i = tid; i < 2112; i += 256) { int vv = mask[i]; if (vv & ~1) local = 1; }
            if (local) atomicOr(&f, 1);
            __syncthreads();
            if (tid == 0) *mflag = f;
        } else if (blockIdx.x == 1) {
            for (int j = tid; j < 512; j += 256) {
                bkg_s[j] = b_kg[j] * scale_g[j >> 6];
                bka_s[j] = b_ka[j] * scale_a[j >> 6];
            }
        }
        return;
    }
    const int K = (z == 5 || z == 7) ? 512 : 256;
    const int N = (z == 5 || z == 7) ? 256 : 512;
    const int k0 = blockIdx.x * 64, n0 = blockIdx.y * 64;
    if (k0 >= K || n0 >= N) return;
    const float* W = z==0?W_qg: z==1?W_kg: z==2?W_qa: z==3?W_ka: z==4?W_v: z==5?W_o: z==6?W_m1: W_m2;
    u16* D        = z==0?T_qg: z==1?T_kg: z==2?T_qa: z==3?T_ka: z==4?T_v: z==5?T_o: z==6?T_m1: T_m2;
    const float* scp = z==1 ? scale_g : z==3 ? scale_a : nullptr;

    __shared__ u16 T[64][80];
    const int cr = tid >> 4, cc = (tid & 15) * 4;
    const float sc = scp ? scp[(n0 + cc) >> 6] : 1.0f;
    #pragma unroll
    for (int i = 0; i < 4; ++i) {
        const int r = cr + i * 16;
        const float4 vv = *(const float4*)(W + (size_t)(k0 + r) * N + n0 + cc);
        T[cc + 0][r] = f2h(vv.x * sc);
        T[cc + 1][r] = f2h(vv.y * sc);
        T[cc + 2][r] = f2h(vv.z * sc);
        T[cc + 3][r] = f2h(vv.w * sc);
    }
    __syncthreads();
    const int nr = tid >> 2, part = (tid & 3) * 16;
    u16* drow = D + (size_t)(n0 + nr) * K + k0 + part;
    *(half8*)(drow)     = *(const half8*)&T[nr][part];
    *(half8*)(drow + 8) = *(const half8*)&T[nr][part + 8];
}

// =======================================================================================
// All 5 projections in ONE dispatch. grid (496, 2). W slice LDS-staged per k-step.
// (r9 exact version — best-measured total.)
// =======================================================================================
__global__ __launch_bounds__(256, 4) void proj_all(
    const float* __restrict__ k_g, const float* __restrict__ k_a,
    const float* __restrict__ v,   const float* __restrict__ q_g,
    const float* __restrict__ q_a,
    const u16* __restrict__ T_kg, const u16* __restrict__ T_ka,
    const u16* __restrict__ T_v,  const u16* __restrict__ T_qg,
    const u16* __restrict__ T_qa,
    const float* __restrict__ bkg_s, const float* __restrict__ bka_s,
    const float* __restrict__ b_v,   const float* __restrict__ b_qg,
    const float* __restrict__ b_qa,
    u16* __restrict__ qcat, u16* __restrict__ kcat, u16* __restrict__ vt)
{
    __shared__ u16 Ws[256 * 36];

    int bx = blockIdx.x;
    int mode, M;
    const float* X; const u16* Wt; const float* bias; u16* out;
    if (bx < 132)      { mode = 2; M = 8448; X = k_g; Wt = T_kg; bias = bkg_s; out = kcat; }
    else if (bx < 264) { mode = 3; M = 8448; X = k_a; Wt = T_ka; bias = bka_s; out = kcat; bx -= 132; }
    else if (bx < 396) { mode = 4; M = 8448; X = v;   Wt = T_v;  bias = b_v;   out = vt;   bx -= 264; }
    else if (bx < 481) { mode = 0; M = 5400; X = q_g; Wt = T_qg; bias = b_qg;  out = qcat; bx -= 396; }
    else               { mode = 1; M = 900;  X = q_a; Wt = T_qa; bias = b_qa;  out = qcat; bx -= 481; }
    const int rows_per_n = (mode == 0) ? 900 : 1408;

    const int tid = threadIdx.x;
    const int w = tid >> 6, lane = tid & 63;
    const int l15 = lane & 15, quad = lane >> 4;
    const int m0 = bx * 64;
    const int nbase = blockIdx.y * 256;
    const int row = m0 + w * 16 + l15;

    const float* xrow = X + (size_t)(row < M ? row : 0) * 256 + quad * 8;
    const u16* wcol = Wt + ((size_t)(nbase + tid) << 8);

    f32x4 o[4][4];
    #pragma unroll
    for (int nt = 0; nt < 4; ++nt)
        #pragma unroll
        for (int t = 0; t < 4; ++t) { o[nt][t][0]=0.f; o[nt][t][1]=0.f; o[nt][t][2]=0.f; o[nt][t][3]=0.f; }

    for (int k0 = 0; k0 < 8; ++k0) {
        {
            const uint4 w0 = *(const uint4*)(wcol + k0 * 32 + 0);
            const uint4 w1 = *(const uint4*)(wcol + k0 * 32 + 8);
            const uint4 w2 = *(const uint4*)(wcol + k0 * 32 + 16);
            const uint4 w3 = *(const uint4*)(wcol + k0 * 32 + 24);
            *(uint4*)&Ws[tid * 36 + 0]  = w0;
            *(uint4*)&Ws[tid * 36 + 8]  = w1;
            *(uint4*)&Ws[tid * 36 + 16] = w2;
            *(uint4*)&Ws[tid * 36 + 24] = w3;
        }
        __syncthreads();

        const float4 a0 = *(const float4*)(xrow + k0 * 32);
        const float4 a1 = *(const float4*)(xrow + k0 * 32 + 4);
        half8 af;
        af[0]=(_Float16)a0.x; af[1]=(_Float16)a0.y; af[2]=(_Float16)a0.z; af[3]=(_Float16)a0.w;
        af[4]=(_Float16)a1.x; af[5]=(_Float16)a1.y; af[6]=(_Float16)a1.z; af[7]=(_Float16)a1.w;

        #pragma unroll
        for (int nt = 0; nt < 4; ++nt)
            #pragma unroll
            for (int t = 0; t < 4; ++t) {
                const half8 bf = *(const half8*)&Ws[(nt * 64 + t * 16 + l15) * 36 + quad * 8];
                o[nt][t] = __builtin_amdgcn_mfma_f32_16x16x32_f16(af, bf, o[nt][t], 0, 0, 0);
            }
        __syncthreads();
    }

    #pragma unroll
    for (int nt = 0; nt < 4; ++nt) {
        const int n0 = nbase + nt * 64;
        const int hh = n0 >> 6;
        float bj[4];
        #pragma unroll
        for (int t = 0; t < 4; ++t) bj[t] = bias[n0 + t * 16 + l15];

        if (mode == 4) {
            const int gr0 = m0 + w * 16 + quad * 4;
            if (gr0 < M) {
                const int nI = gr0 / rows_per_n;
                const int rr = gr0 - nI * rows_per_n;
                u16* vb = out + (size_t)(hh * 6 + nI) * 64 * 1408;
                #pragma unroll
                for (int t = 0; t < 4; ++t) {
                    const int d = t * 16 + l15;
                    ushort4 pk;
                    pk.x = f2h(o[nt][t][0] + bj[t]);
                    pk.y = f2h(o[nt][t][1] + bj[t]);
                    pk.z = f2h(o[nt][t][2] + bj[t]);
                    pk.w = f2h(o[nt][t][3] + bj[t]);
                    *(ushort4*)&vb[(size_t)d * 1408 + rr] = pk;
                }
            }
        } else if (mode == 1) {
            #pragma unroll
            for (int r = 0; r < 4; ++r) {
                const int gr = m0 + w * 16 + quad * 4 + r;
                if (gr < M) {
                    for (int nb = 0; nb < 6; ++nb) {
                        u16* qb = out + (((size_t)(hh * 6 + nb) * 900 + gr) << 7) + 64;
                        #pragma unroll
                        for (int t = 0; t < 4; ++t)
                            qb[t * 16 + l15] = f2h(o[nt][t][r] + bj[t]);
                    }
                }
            }
        } else {
            const size_t kdim = (mode == 0) ? 900 : 1408;
            const int doff = (mode == 3) ? 64 : 0;
            #pragma unroll
            for (int r = 0; r < 4; ++r) {
                const int gr = m0 + w * 16 + quad * 4 + r;
                if (gr < M) {
                    const int nI = gr / rows_per_n;
                    const int rr = gr - nI * rows_per_n;
                    u16* ob = out + (((size_t)(hh * 6 + nI) * kdim + rr) << 7) + doff;
                    #pragma unroll
                    for (int t = 0; t < 4; ++t)
                        ob[t * 16 + l15] = f2h(o[nt][t][r] + bj[t]);
                }
            }
        }
    }
}

// =======================================================================================
// MFMA flash attention — r12 measured-best: 512-thread / 8-wave / 128-q-row blocks.
// (52.4 µs, VGPR 56, grid 768.) Unchanged.
// =======================================================================================
__global__ __launch_bounds__(512, 4) void attn_kernel(
    const u16* __restrict__ qcat, const u16* __restrict__ kcat,
    const u16* __restrict__ vt, const void* __restrict__ maskp,
    const int* __restrict__ mflag,
    u16* __restrict__ Opart, float* __restrict__ lpart)
{
    __shared__ __align__(16) u16 Ks[64 * 136];   // 17.4 KB
    __shared__ __align__(16) u16 Vs[64 * 72];    //  9.2 KB
    __shared__ __align__(16) u16 Ps[8][1216];    // 19.4 KB, row*72 + (row>>2)*16 + col
    __shared__ float Mb[64];

    const int flat = blockIdx.x;                 // 768 = 48 hn x 8 qt x 2 sp
    const int hn_i = (flat & 7) + 8 * ((flat >> 3) % 6);
    const int rest = flat / 48;                  // 0..15
    const int qt = rest & 7;
    const int sp = rest >> 3;
    const int n = hn_i - (hn_i / 6) * 6;

    const int q0 = qt * 128;
    const int tid = threadIdx.x;
    const int w = tid >> 6, lane = tid & 63;     // w 0..7
    const int l15 = lane & 15, quad = lane >> 4;
    const bool m8 = (*mflag != 0);
    const size_t hn = (size_t)hn_i;

    const u16* kbase = kcat + ((hn * 1408) << 7);
    const u16* vbase = vt + hn * 64 * 1408;
    const unsigned char* mB = (const unsigned char*)maskp;
    const int* mI = (const int*)maskp;
    const int mko = n * 1408;

    const int krow_s = tid >> 4;                 // 0..31 (two K rows per thread)
    const int kcol_s = (tid & 15) * 8;
    const int vrow_s = tid >> 3;                 // 0..63 (one V row per thread)
    const int vcol_s = (tid & 7) * 8;

    half8 qf[4];
    {
        const int gq = q0 + w * 16 + l15;
        if (gq < 900) {
            const u16* qrow = qcat + ((hn * 900 + gq) << 7) + quad * 8;
            #pragma unroll
            for (int k0 = 0; k0 < 4; ++k0)
                qf[k0] = *(const half8*)(qrow + k0 * 32);
        } else {
            #pragma unroll
            for (int k0 = 0; k0 < 4; ++k0)
                #pragma unroll
                for (int j = 0; j < 8; ++j) qf[k0][j] = (_Float16)0.0f;
        }
    }

    // ones-column B fragment: B[k][0]=1 for all k -> D[:,0] = row sums of A
    half8 onesb;
    {
        const _Float16 ov = (l15 == 0) ? (_Float16)1.0f : (_Float16)0.0f;
        #pragma unroll
        for (int j = 0; j < 8; ++j) onesb[j] = ov;
    }

    f32x4 o[4];
    f32x4 l16;
    #pragma unroll
    for (int t = 0; t < 4; ++t) { o[t][0]=0.f; o[t][1]=0.f; o[t][2]=0.f; o[t][3]=0.f; }
    l16[0]=0.f; l16[1]=0.f; l16[2]=0.f; l16[3]=0.f;

    // ---- prefetch chunk 0 into registers ----
    uint4 kA, kB, vA;
    float mreg = 0.0f;
    {
        const int k0c = sp * 11 * 64;
        kA = *(const uint4*)(kbase + ((size_t)(k0c +  0 + krow_s) << 7) + kcol_s);
        kB = *(const uint4*)(kbase + ((size_t)(k0c + 32 + krow_s) << 7) + kcol_s);
        vA = *(const uint4*)(vbase + (size_t)(vrow_s) * 1408 + k0c + vcol_s);
        if (tid < 64) {
            const int ki = mko + k0c + tid;
            const int mv = m8 ? (int)mB[ki] : mI[ki];
            mreg = mv ? -1e30f : 0.0f;
        }
    }

    for (int cc = 0; cc < 11; ++cc) {
        // ---- stage prefetched registers to LDS ----
        *(uint4*)&Ks[( 0 + krow_s) * 136 + kcol_s] = kA;
        *(uint4*)&Ks[(32 + krow_s) * 136 + kcol_s] = kB;
        *(uint4*)&Vs[vrow_s * 72 + vcol_s] = vA;
        if (tid < 64) Mb[tid] = mreg;
        __syncthreads();

        // ---- issue next chunk's global loads (in flight under compute) ----
        if (cc < 10) {
            const int k0n = (sp * 11 + cc + 1) * 64;
            kA = *(const uint4*)(kbase + ((size_t)(k0n +  0 + krow_s) << 7) + kcol_s);
            kB = *(const uint4*)(kbase + ((size_t)(k0n + 32 + krow_s) << 7) + kcol_s);
            vA = *(const uint4*)(vbase + (size_t)(vrow_s) * 1408 + k0n + vcol_s);
            if (tid < 64) {
                const int ki = mko + k0n + tid;
                const int mv = m8 ? (int)mB[ki] : mI[ki];
                mreg = mv ? -1e30f : 0.0f;
            }
        }

        // ---- QK^T: accumulator seeded with mask bias ----
        f32x4 s[4];
        #pragma unroll
        for (int t = 0; t < 4; ++t) {
            const float mbv = Mb[t * 16 + l15];
            s[t][0]=mbv; s[t][1]=mbv; s[t][2]=mbv; s[t][3]=mbv;
        }
        #pragma unroll
        for (int k0 = 0; k0 < 4; ++k0)
            #pragma unroll
            for (int t = 0; t < 4; ++t) {
                const half8 kf = *(const half8*)&Ks[(t * 16 + l15) * 136 + k0 * 32 + quad * 8];
                s[t] = __builtin_amdgcn_mfma_f32_16x16x32_f16(qf[k0], kf, s[t], 0, 0, 0);
            }

        // ---- softmax-lite: plain exp, P -> LDS (skewed layout) ----
        #pragma unroll
        for (int r = 0; r < 4; ++r) {
            const float p0 = __expf(s[0][r]);
            const float p1 = __expf(s[1][r]);
            const float p2 = __expf(s[2][r]);
            const float p3 = __expf(s[3][r]);
            u16* pr = &Ps[w][(quad * 4 + r) * 72 + quad * 16 + l15];
            pr[0]  = f2h(p0);
            pr[16] = f2h(p1);
            pr[32] = f2h(p2);
            pr[48] = f2h(p3);
        }

        const u16* prow = &Ps[w][l15 * 72 + (l15 >> 2) * 16 + quad * 8];
        const half8 pa0 = *(const half8*)(prow);
        const half8 pa1 = *(const half8*)(prow + 32);

        // row sums via ones-column MFMA (accumulated across all chunks)
        l16 = __builtin_amdgcn_mfma_f32_16x16x32_f16(pa0, onesb, l16, 0, 0, 0);
        l16 = __builtin_amdgcn_mfma_f32_16x16x32_f16(pa1, onesb, l16, 0, 0, 0);

        #pragma unroll
        for (int t = 0; t < 4; ++t) {
            const half8 v0 = *(const half8*)&Vs[(t * 16 + l15) * 72 + quad * 8];
            const half8 v1 = *(const half8*)&Vs[(t * 16 + l15) * 72 + 32 + quad * 8];
            o[t] = __builtin_amdgcn_mfma_f32_16x16x32_f16(pa0, v0, o[t], 0, 0, 0);
            o[t] = __builtin_amdgcn_mfma_f32_16x16x32_f16(pa1, v1, o[t], 0, 0, 0);
        }
        __syncthreads();
    }

    const int p = sp * 48 + hn_i;
    #pragma unroll
    for (int r = 0; r < 4; ++r) {
        const int gq = q0 + w * 16 + quad * 4 + r;
        if (gq < 900) {
            u16* db = Opart + ((size_t)p * 900 + gq) * 64 + l15;
            db[0]  = f2h(o[0][r]);
            db[16] = f2h(o[1][r]);
            db[32] = f2h(o[2][r]);
            db[48] = f2h(o[3][r]);
            if (l15 == 0) lpart[p * 900 + gq] = l16[r];
        }
    }
}

// =======================================================================================
// Fused epilogue megakernel — ROUND 14: split-K. 512 threads / 8 waves, 4 rows/block
// (grid 225). Waves 0-3 and 4-7 each run HALF of every phase's k-loop (the serial
// L2-load chain that r13 proved is row-count-invariant), then LDS-reduce partial
// accumulators. Chain length per phase halves; weight traffic unchanged.
// All __syncthreads are block-uniform.
// =======================================================================================
__global__ __launch_bounds__(512) void epi_mega(
    const u16* __restrict__ Opart, const float* __restrict__ lpart,
    const u16* __restrict__ T_o,
    const u16* __restrict__ T_m1, const u16* __restrict__ T_m2,
    const float* __restrict__ b_o, const float* __restrict__ q_a,
    const float* __restrict__ ln1_g, const float* __restrict__ ln1_b,
    const float* __restrict__ b_m1, const float* __restrict__ b_m2,
    const float* __restrict__ ln2_g, const float* __restrict__ ln2_b,
    float* __restrict__ outf)
{
    __shared__ u16 A16[4][520];       // 4.2 KB combined attention rows
    __shared__ u16 Z1[16][264];       // 8.4 KB
    __shared__ u16 H[16][520];        // 16.6 KB
    __shared__ float Red[256 * 32];   // 32 KB split-K partial accumulators
    __shared__ float Ssum[4][16];
    __shared__ float Ssq[4][16];

    const int tid = threadIdx.x;
    const int w = tid >> 6, lane = tid & 63;     // w 0..7
    const int w4 = w & 3, kh = w >> 2;           // col-wave, k-half
    const int t256 = tid & 255;                  // index within half
    const int l15 = lane & 15, quad = lane >> 4;
    const int m0 = blockIdx.x * 4;

    // ================= Prologue: merge 12 partials for this block's 4 rows ============
    {
        const int r = tid >> 7;           // 0..3
        const int cg = tid & 127;         // col-group (4 cols each)
        const int c4 = cg * 4;
        const int hh = cg >> 4;           // head
        const int d4 = (cg & 15) * 4;     // d-offset within head
        const int q = m0 + r;             // 900 % 4 == 0 -> always < 900
        float l = 0.f;
        float a0 = 0.f, a1 = 0.f, a2 = 0.f, a3 = 0.f;
        #pragma unroll
        for (int s = 0; s < 12; ++s) {
            const int p = ((s & 1) ? 48 : 0) + hh * 6 + (s >> 1);
            l += lpart[p * 900 + q];
            const ushort4 t0 = *(const ushort4*)&Opart[((size_t)p * 900 + q) * 64 + d4];
            a0 += h2f(t0.x); a1 += h2f(t0.y); a2 += h2f(t0.z); a3 += h2f(t0.w);
        }
        const float inv = 1.0f / fmaxf(l, 1e-30f);
        ushort4 o0;
        o0.x = f2h(a0 * inv); o0.y = f2h(a1 * inv); o0.z = f2h(a2 * inv); o0.w = f2h(a3 * inv);
        *(ushort4*)&A16[r][c4] = o0;
    }
    __syncthreads();

    // ================= Phase A: out-proj + LN1 (split-K 8+8) =================
    {
        f32x4 acc[4];
        #pragma unroll
        for (int t = 0; t < 4; ++t) { acc[t][0]=0.f; acc[t][1]=0.f; acc[t][2]=0.f; acc[t][3]=0.f; }

        const int kbase = kh * 8;
        #pragma unroll
        for (int kk = 0; kk < 8; ++kk) {
            const int k0 = kbase + kk;
            const half8 af = *(const half8*)&A16[l15 & 3][k0 * 32 + quad * 8];
            #pragma unroll
            for (int t = 0; t < 4; ++t) {
                const int nn = w4 * 64 + t * 16 + l15;
                const half8 bf = *(const half8*)(T_o + (size_t)nn * 512 + k0 * 32 + quad * 8);
                acc[t] = __builtin_amdgcn_mfma_f32_16x16x32_f16(af, bf, acc[t], 0, 0, 0);
            }
        }

        // reduce the two k-halves
        if (kh == 1) {
            #pragma unroll
            for (int t = 0; t < 4; ++t)
                #pragma unroll
                for (int r = 0; r < 4; ++r)
                    Red[t256 * 16 + t * 4 + r] = acc[t][r];
        }
        __syncthreads();
        if (kh == 0) {
            #pragma unroll
            for (int t = 0; t < 4; ++t)
                #pragma unroll
                for (int r = 0; r < 4; ++r)
                    acc[t][r] += Red[t256 * 16 + t * 4 + r];
        }

        float vals[4][4];
        #pragma unroll
        for (int r = 0; r < 4; ++r) {
            const int row = m0 + ((quad * 4 + r) & 3);
            float s = 0.f, sq = 0.f;
            #pragma unroll
            for (int t = 0; t < 4; ++t) {
                const int col = w4 * 64 + t * 16 + l15;
                const float x = acc[t][r] + b_o[col] + q_a[(size_t)row * 256 + col];
                vals[r][t] = x; s += x; sq += x * x;
            }
            s = sum16(s); sq = sum16(sq);
            if (l15 == 0 && kh == 0) { Ssum[w4][quad * 4 + r] = s; Ssq[w4][quad * 4 + r] = sq; }
        }
        __syncthreads();

        if (kh == 0) {
            #pragma unroll
            for (int r = 0; r < 4; ++r) {
                const int rl = quad * 4 + r;
                const float st = Ssum[0][rl] + Ssum[1][rl] + Ssum[2][rl] + Ssum[3][rl];
                const float qt = Ssq[0][rl] + Ssq[1][rl] + Ssq[2][rl] + Ssq[3][rl];
                const float mean = st * (1.0f / 256.0f);
                const float var  = qt * (1.0f / 256.0f) - mean * mean;
                const float inv  = rsqrtf(var + 1e-5f);
                #pragma unroll
                for (int t = 0; t < 4; ++t) {
                    const int col = w4 * 64 + t * 16 + l15;
                    const float z = (vals[r][t] - mean) * inv * ln1_g[col] + ln1_b[col];
                    Z1[rl][col] = f2h(z);
                }
            }
        }
        __syncthreads();
    }

    // ================= Phase B: MLP1 + gelu (split-K 4+4) =================
    {
        f32x4 acc[8];
        #pragma unroll
        for (int t = 0; t < 8; ++t) { acc[t][0]=0.f; acc[t][1]=0.f; acc[t][2]=0.f; acc[t][3]=0.f; }

        const int kbase = kh * 4;
        #pragma unroll
        for (int kk = 0; kk < 4; ++kk) {
            const int k0 = kbase + kk;
            const half8 af = *(const half8*)&Z1[l15][k0 * 32 + quad * 8];
            #pragma unroll
            for (int t = 0; t < 8; ++t) {
                const int nn = w4 * 128 + t * 16 + l15;
                const half8 bf = *(const half8*)(T_m1 + (size_t)nn * 256 + k0 * 32 + quad * 8);
                acc[t] = __builtin_amdgcn_mfma_f32_16x16x32_f16(af, bf, acc[t], 0, 0, 0);
            }
        }

        if (kh == 1) {
            #pragma unroll
            for (int t = 0; t < 8; ++t)
                #pragma unroll
                for (int r = 0; r < 4; ++r)
                    Red[t256 * 32 + t * 4 + r] = acc[t][r];
        }
        __syncthreads();
        if (kh == 0) {
            #pragma unroll
            for (int r = 0; r < 4; ++r) {
                const int rl = quad * 4 + r;
                #pragma unroll
                for (int t = 0; t < 8; ++t) {
                    const int col = w4 * 128 + t * 16 + l15;
                    const float x = acc[t][r] + Red[t256 * 32 + t * 4 + r] + b_m1[col];
                    H[rl][col] = f2h(0.5f * x * (1.0f + erff(x * 0.70710678118654752f)));
                }
            }
        }
        __syncthreads();
    }

    // ================= Phase C: MLP2 + residual + LN2 (split-K 8+8) =================
    {
        f32x4 acc[4];
        #pragma unroll
        for (int t = 0; t < 4; ++t) { acc[t][0]=0.f; acc[t][1]=0.f; acc[t][2]=0.f; acc[t][3]=0.f; }

        const int kbase = kh * 8;
        #pragma unroll
        for (int kk = 0; kk < 8; ++kk) {
            const int k0 = kbase + kk;
            const half8 af = *(const half8*)&H[l15][k0 * 32 + quad * 8];
            #pragma unroll
            for (int t = 0; t < 4; ++t) {
                const int nn = w4 * 64 + t * 16 + l15;
                const half8 bf = *(const half8*)(T_m2 + (size_t)nn * 512 + k0 * 32 + quad * 8);
                acc[t] = __builtin_amdgcn_mfma_f32_16x16x32_f16(af, bf, acc[t], 0, 0, 0);
            }
        }

        if (kh == 1) {
            #pragma unroll
            for (int t = 0; t < 4; ++t)
                #pragma unroll
                for (int r = 0; r < 4; ++r)
                    Red[t256 * 16 + t * 4 + r] = acc[t][r];
        }
        __syncthreads();
        if (kh == 0) {
            #pragma unroll
            for (int t = 0; t < 4; ++t)
                #pragma unroll
                for (int r = 0; r < 4; ++r)
                    acc[t][r] += Red[t256 * 16 + t * 4 + r];
        }

        float vals[4][4];
        #pragma unroll
        for (int r = 0; r < 4; ++r) {
            const int rl = quad * 4 + r;
            float s = 0.f, sq = 0.f;
            #pragma unroll
            for (int t = 0; t < 4; ++t) {
                const int col = w4 * 64 + t * 16 + l15;
                const float x = acc[t][r] + b_m2[col] + h2f(Z1[rl & 3][col]);
                vals[r][t] = x; s += x; sq += x * x;
            }
            s = sum16(s); sq = sum16(sq);
            if (l15 == 0 && kh == 0) { Ssum[w4][rl] = s; Ssq[w4][rl] = sq; }
        }
        __syncthreads();

        if (kh == 0) {
            #pragma unroll
            for (int r = 0; r < 4; ++r) {
                const int rl = quad * 4 + r;
                const float st = Ssum[0][rl] + Ssum[1][rl] + Ssum[2][rl] + Ssum[3][rl];
                const float qt = Ssq[0][rl] + Ssq[1][rl] + Ssq[2][rl] + Ssq[3][rl];
                const float mean = st * (1.0f / 256.0f);
                const float var  = qt * (1.0f / 256.0f) - mean * mean;
                const float inv  = rsqrtf(var + 1e-5f);
                const int row = m0 + rl;
                if (rl < 4 && row < 900) {
                    #pragma unroll
                    for (int t = 0; t < 4; ++t) {
                        const int col = w4 * 64 + t * 16 + l15;
                        outf[(size_t)row * 256 + col] = (vals[r][t] - mean) * inv * ln2_g[col] + ln2_b[col];
                    }
                }
            }
        }
    }
}

extern "C" void kernel_launch(void* const* d_in, const int* in_sizes, int n_in,
                              void* d_out, int out_size, void* d_ws, size_t ws_size,
                              hipStream_t stream)
{
    const float* k_g  = (const float*)d_in[0];
    const float* q_g  = (const float*)d_in[1];
    const float* k_a  = (const float*)d_in[2];
    const float* q_a  = (const float*)d_in[3];
    const float* v    = (const float*)d_in[4];
    const void*  mask = d_in[5];
    const float* W_qg = (const float*)d_in[6];
    const float* b_qg = (const float*)d_in[7];
    const float* W_kg = (const float*)d_in[8];
    const float* b_kg = (const float*)d_in[9];
    const float* W_qa = (const float*)d_in[10];
    const float* b_qa = (const float*)d_in[11];
    const float* W_ka = (const float*)d_in[12];
    const float* b_ka = (const float*)d_in[13];
    const float* W_v  = (const float*)d_in[14];
    const float* b_v  = (const float*)d_in[15];
    const float* W_o  = (const float*)d_in[16];
    const float* b_o  = (const float*)d_in[17];
    const float* ln1_g = (const float*)d_in[18];
    const float* ln1_b = (const float*)d_in[19];
    const float* W_m1 = (const float*)d_in[20];
    const float* b_m1 = (const float*)d_in[21];
    const float* W_m2 = (const float*)d_in[22];
    const float* b_m2 = (const float*)d_in[23];
    const float* ln2_g = (const float*)d_in[24];
    const float* ln2_b = (const float*)d_in[25];
    const float* scale_g = (const float*)d_in[26];
    const float* scale_a = (const float*)d_in[27];

    char* ws = (char*)d_ws;
    size_t off = 0;
    auto alloc = [&](size_t bytes) -> void* {
        void* p = ws + off;
        off += (bytes + 255) & ~(size_t)255;
        return p;
    };
    u16*   qcat  = (u16*)  alloc((size_t)8 * 6 * 900  * 128 * 2);
    u16*   kcat  = (u16*)  alloc((size_t)8 * 6 * 1408 * 128 * 2);
    u16*   vt    = (u16*)  alloc((size_t)8 * 6 * 64 * 1408 * 2);
    u16*   Tw[8];
    for (int i = 0; i < 8; ++i) Tw[i] = (u16*)alloc((size_t)512 * 256 * 2);
    float* bkg_s = (float*)alloc((size_t)512 * 4);
    float* bka_s = (float*)alloc((size_t)512 * 4);
    int*   mflag = (int*)  alloc(256);
    u16*   Opart = (u16*)  alloc((size_t)96 * 900 * 64 * 2);
    float* lpart = (float*)alloc((size_t)96 * 900 * 4);

    prep_kernel<<<dim3(8, 8, 9), 256, 0, stream>>>(
        W_qg, W_kg, W_qa, W_ka, W_v, W_o, W_m1, W_m2,
        Tw[0], Tw[1], Tw[2], Tw[3], Tw[4], Tw[5], Tw[6], Tw[7],
        scale_g, scale_a, b_kg, b_ka, bkg_s, bka_s, (const int*)mask, mflag);

    proj_all<<<dim3(496, 2), 256, 0, stream>>>(
        k_g, k_a, v, q_g, q_a,
        Tw[1], Tw[3], Tw[4], Tw[0], Tw[2],
        bkg_s, bka_s, b_v, b_qg, b_qa,
        qcat, kcat, vt);

    attn_kernel<<<768, 512, 0, stream>>>(qcat, kcat, vt, mask, mflag, Opart, lpart);

    epi_mega<<<225, 512, 0, stream>>>(
        Opart, lpart, Tw[5], Tw[6], Tw[7],
        b_o, q_a, ln1_g, ln1_b, b_m1, b_m2, ln2_g, ln2_b,
        (float*)d_out);
}

// Round 15
// 237.751 us; speedup vs baseline: 1.0608x; 1.0257x over previous
//
#include <hip/hip_runtime.h>
#include <stdint.h>

typedef unsigned short u16;
typedef _Float16 half8 __attribute__((ext_vector_type(8)));
typedef _Float16 half4 __attribute__((ext_vector_type(4)));
typedef _Float16 half2 __attribute__((ext_vector_type(2)));
typedef float f32x4 __attribute__((ext_vector_type(4)));

__device__ __forceinline__ u16 f2h(float f) {
    _Float16 h = (_Float16)f; u16 u; __builtin_memcpy(&u, &h, 2); return u;
}
__device__ __forceinline__ float h2f(u16 u) {
    _Float16 h; __builtin_memcpy(&h, &u, 2); return (float)h;
}

// ---------- DPP 16-lane sum (pure VALU) ----------
template<int CTRL>
__device__ __forceinline__ float dppf(float x) {
    return __builtin_bit_cast(float,
        __builtin_amdgcn_update_dpp(0, __builtin_bit_cast(int, x), CTRL, 0xF, 0xF, false));
}
__device__ __forceinline__ float sum16(float x) {
    x += dppf<0xB1>(x);
    x += dppf<0x4E>(x);
    x += dppf<0x124>(x);
    x += dppf<0x128>(x);
    return x;
}

// =======================================================================================
// Prep: all 8 weights -> fp16 transposed [N][K] (+scale fold), scaled biases, mask flag.
// =======================================================================================
__global__ __launch_bounds__(256) void prep_kernel(
    const float* __restrict__ W_qg, const float* __restrict__ W_kg,
    const float* __restrict__ W_qa, const float* __restrict__ W_ka,
    const float* __restrict__ W_v,  const float* __restrict__ W_o,
    const float* __restrict__ W_m1, const float* __restrict__ W_m2,
    u16* __restrict__ T_qg, u16* __restrict__ T_kg, u16* __restrict__ T_qa,
    u16* __restrict__ T_ka, u16* __restrict__ T_v,  u16* __restrict__ T_o,
    u16* __restrict__ T_m1, u16* __restrict__ T_m2,
    const float* __restrict__ scale_g, const float* __restrict__ scale_a,
    const float* __restrict__ b_kg, const float* __restrict__ b_ka,
    float* __restrict__ bkg_s, float* __restrict__ bka_s,
    const int* __restrict__ mask, int* __restrict__ mflag)
{
    const int z = blockIdx.z;
    const int tid = threadIdx.x;
    if (z == 8) {
        if (blockIdx.y != 0) return;
        if (blockIdx.x == 0) {
            __shared__ int f;
            if (tid == 0) f = 0;
            __syncthreads();
            int local = 0;
            for (int i = tid; i < 2112; i += 256) { int vv = mask[i]; if (vv & ~1) local = 1; }
            if (local) atomicOr(&f, 1);
            __syncthreads();
            if (tid == 0) *mflag = f;
        } else if (blockIdx.x == 1) {
            for (int j = tid; j < 512; j += 256) {
                bkg_s[j] = b_kg[j] * scale_g[j >> 6];
                bka_s[j] = b_ka[j] * scale_a[j >> 6];
            }
        }
        return;
    }
    const int K = (z == 5 || z == 7) ? 512 : 256;
    const int N = (z == 5 || z == 7) ? 256 : 512;
    const int k0 = blockIdx.x * 64, n0 = blockIdx.y * 64;
    if (k0 >= K || n0 >= N) return;
    const float* W = z==0?W_qg: z==1?W_kg: z==2?W_qa: z==3?W_ka: z==4?W_v: z==5?W_o: z==6?W_m1: W_m2;
    u16* D        = z==0?T_qg: z==1?T_kg: z==2?T_qa: z==3?T_ka: z==4?T_v: z==5?T_o: z==6?T_m1: T_m2;
    const float* scp = z==1 ? scale_g : z==3 ? scale_a : nullptr;

    __shared__ u16 T[64][80];
    const int cr = tid >> 4, cc = (tid & 15) * 4;
    const float sc = scp ? scp[(n0 + cc) >> 6] : 1.0f;
    #pragma unroll
    for (int i = 0; i < 4; ++i) {
        const int r = cr + i * 16;
        const float4 vv = *(const float4*)(W + (size_t)(k0 + r) * N + n0 + cc);
        T[cc + 0][r] = f2h(vv.x * sc);
        T[cc + 1][r] = f2h(vv.y * sc);
        T[cc + 2][r] = f2h(vv.z * sc);
        T[cc + 3][r] = f2h(vv.w * sc);
    }
    __syncthreads();
    const int nr = tid >> 2, part = (tid & 3) * 16;
    u16* drow = D + (size_t)(n0 + nr) * K + k0 + part;
    *(half8*)(drow)     = *(const half8*)&T[nr][part];
    *(half8*)(drow + 8) = *(const half8*)&T[nr][part + 8];
}

// =======================================================================================
// All 5 projections in ONE dispatch. grid (496, 2). W slice LDS-staged per k-step.
// (r9 exact version — best-measured total.)
// =======================================================================================
__global__ __launch_bounds__(256, 4) void proj_all(
    const float* __restrict__ k_g, const float* __restrict__ k_a,
    const float* __restrict__ v,   const float* __restrict__ q_g,
    const float* __restrict__ q_a,
    const u16* __restrict__ T_kg, const u16* __restrict__ T_ka,
    const u16* __restrict__ T_v,  const u16* __restrict__ T_qg,
    const u16* __restrict__ T_qa,
    const float* __restrict__ bkg_s, const float* __restrict__ bka_s,
    const float* __restrict__ b_v,   const float* __restrict__ b_qg,
    const float* __restrict__ b_qa,
    u16* __restrict__ qcat, u16* __restrict__ kcat, u16* __restrict__ vt)
{
    __shared__ u16 Ws[256 * 36];

    int bx = blockIdx.x;
    int mode, M;
    const float* X; const u16* Wt; const float* bias; u16* out;
    if (bx < 132)      { mode = 2; M = 8448; X = k_g; Wt = T_kg; bias = bkg_s; out = kcat; }
    else if (bx < 264) { mode = 3; M = 8448; X = k_a; Wt = T_ka; bias = bka_s; out = kcat; bx -= 132; }
    else if (bx < 396) { mode = 4; M = 8448; X = v;   Wt = T_v;  bias = b_v;   out = vt;   bx -= 264; }
    else if (bx < 481) { mode = 0; M = 5400; X = q_g; Wt = T_qg; bias = b_qg;  out = qcat; bx -= 396; }
    else               { mode = 1; M = 900;  X = q_a; Wt = T_qa; bias = b_qa;  out = qcat; bx -= 481; }
    const int rows_per_n = (mode == 0) ? 900 : 1408;

    const int tid = threadIdx.x;
    const int w = tid >> 6, lane = tid & 63;
    const int l15 = lane & 15, quad = lane >> 4;
    const int m0 = bx * 64;
    const int nbase = blockIdx.y * 256;
    const int row = m0 + w * 16 + l15;

    const float* xrow = X + (size_t)(row < M ? row : 0) * 256 + quad * 8;
    const u16* wcol = Wt + ((size_t)(nbase + tid) << 8);

    f32x4 o[4][4];
    #pragma unroll
    for (int nt = 0; nt < 4; ++nt)
        #pragma unroll
        for (int t = 0; t < 4; ++t) { o[nt][t][0]=0.f; o[nt][t][1]=0.f; o[nt][t][2]=0.f; o[nt][t][3]=0.f; }

    for (int k0 = 0; k0 < 8; ++k0) {
        {
            const uint4 w0 = *(const uint4*)(wcol + k0 * 32 + 0);
            const uint4 w1 = *(const uint4*)(wcol + k0 * 32 + 8);
            const uint4 w2 = *(const uint4*)(wcol + k0 * 32 + 16);
            const uint4 w3 = *(const uint4*)(wcol + k0 * 32 + 24);
            *(uint4*)&Ws[tid * 36 + 0]  = w0;
            *(uint4*)&Ws[tid * 36 + 8]  = w1;
            *(uint4*)&Ws[tid * 36 + 16] = w2;
            *(uint4*)&Ws[tid * 36 + 24] = w3;
        }
        __syncthreads();

        const float4 a0 = *(const float4*)(xrow + k0 * 32);
        const float4 a1 = *(const float4*)(xrow + k0 * 32 + 4);
        half8 af;
        af[0]=(_Float16)a0.x; af[1]=(_Float16)a0.y; af[2]=(_Float16)a0.z; af[3]=(_Float16)a0.w;
        af[4]=(_Float16)a1.x; af[5]=(_Float16)a1.y; af[6]=(_Float16)a1.z; af[7]=(_Float16)a1.w;

        #pragma unroll
        for (int nt = 0; nt < 4; ++nt)
            #pragma unroll
            for (int t = 0; t < 4; ++t) {
                const half8 bf = *(const half8*)&Ws[(nt * 64 + t * 16 + l15) * 36 + quad * 8];
                o[nt][t] = __builtin_amdgcn_mfma_f32_16x16x32_f16(af, bf, o[nt][t], 0, 0, 0);
            }
        __syncthreads();
    }

    #pragma unroll
    for (int nt = 0; nt < 4; ++nt) {
        const int n0 = nbase + nt * 64;
        const int hh = n0 >> 6;
        float bj[4];
        #pragma unroll
        for (int t = 0; t < 4; ++t) bj[t] = bias[n0 + t * 16 + l15];

        if (mode == 4) {
            const int gr0 = m0 + w * 16 + quad * 4;
            if (gr0 < M) {
                const int nI = gr0 / rows_per_n;
                const int rr = gr0 - nI * rows_per_n;
                u16* vb = out + (size_t)(hh * 6 + nI) * 64 * 1408;
                #pragma unroll
                for (int t = 0; t < 4; ++t) {
                    const int d = t * 16 + l15;
                    ushort4 pk;
                    pk.x = f2h(o[nt][t][0] + bj[t]);
                    pk.y = f2h(o[nt][t][1] + bj[t]);
                    pk.z = f2h(o[nt][t][2] + bj[t]);
                    pk.w = f2h(o[nt][t][3] + bj[t]);
                    *(ushort4*)&vb[(size_t)d * 1408 + rr] = pk;
                }
            }
        } else if (mode == 1) {
            #pragma unroll
            for (int r = 0; r < 4; ++r) {
                const int gr = m0 + w * 16 + quad * 4 + r;
                if (gr < M) {
                    for (int nb = 0; nb < 6; ++nb) {
                        u16* qb = out + (((size_t)(hh * 6 + nb) * 900 + gr) << 7) + 64;
                        #pragma unroll
                        for (int t = 0; t < 4; ++t)
                            qb[t * 16 + l15] = f2h(o[nt][t][r] + bj[t]);
                    }
                }
            }
        } else {
            const size_t kdim = (mode == 0) ? 900 : 1408;
            const int doff = (mode == 3) ? 64 : 0;
            #pragma unroll
            for (int r = 0; r < 4; ++r) {
                const int gr = m0 + w * 16 + quad * 4 + r;
                if (gr < M) {
                    const int nI = gr / rows_per_n;
                    const int rr = gr - nI * rows_per_n;
                    u16* ob = out + (((size_t)(hh * 6 + nI) * kdim + rr) << 7) + doff;
                    #pragma unroll
                    for (int t = 0; t < 4; ++t)
                        ob[t * 16 + l15] = f2h(o[nt][t][r] + bj[t]);
                }
            }
        }
    }
}

// =======================================================================================
// MFMA flash attention — r12 measured-best: 512-thread / 8-wave / 128-q-row blocks.
// (52.4 µs, VGPR 56, grid 768.)
// =======================================================================================
__global__ __launch_bounds__(512, 4) void attn_kernel(
    const u16* __restrict__ qcat, const u16* __restrict__ kcat,
    const u16* __restrict__ vt, const void* __restrict__ maskp,
    const int* __restrict__ mflag,
    u16* __restrict__ Opart, float* __restrict__ lpart)
{
    __shared__ __align__(16) u16 Ks[64 * 136];   // 17.4 KB
    __shared__ __align__(16) u16 Vs[64 * 72];    //  9.2 KB
    __shared__ __align__(16) u16 Ps[8][1216];    // 19.4 KB, row*72 + (row>>2)*16 + col
    __shared__ float Mb[64];

    const int flat = blockIdx.x;                 // 768 = 48 hn x 8 qt x 2 sp
    const int hn_i = (flat & 7) + 8 * ((flat >> 3) % 6);
    const int rest = flat / 48;                  // 0..15
    const int qt = rest & 7;
    const int sp = rest >> 3;
    const int n = hn_i - (hn_i / 6) * 6;

    const int q0 = qt * 128;
    const int tid = threadIdx.x;
    const int w = tid >> 6, lane = tid & 63;     // w 0..7
    const int l15 = lane & 15, quad = lane >> 4;
    const bool m8 = (*mflag != 0);
    const size_t hn = (size_t)hn_i;

    const u16* kbase = kcat + ((hn * 1408) << 7);
    const u16* vbase = vt + hn * 64 * 1408;
    const unsigned char* mB = (const unsigned char*)maskp;
    const int* mI = (const int*)maskp;
    const int mko = n * 1408;

    const int krow_s = tid >> 4;                 // 0..31 (two K rows per thread)
    const int kcol_s = (tid & 15) * 8;
    const int vrow_s = tid >> 3;                 // 0..63 (one V row per thread)
    const int vcol_s = (tid & 7) * 8;

    half8 qf[4];
    {
        const int gq = q0 + w * 16 + l15;
        if (gq < 900) {
            const u16* qrow = qcat + ((hn * 900 + gq) << 7) + quad * 8;
            #pragma unroll
            for (int k0 = 0; k0 < 4; ++k0)
                qf[k0] = *(const half8*)(qrow + k0 * 32);
        } else {
            #pragma unroll
            for (int k0 = 0; k0 < 4; ++k0)
                #pragma unroll
                for (int j = 0; j < 8; ++j) qf[k0][j] = (_Float16)0.0f;
        }
    }

    // ones-column B fragment: B[k][0]=1 for all k -> D[:,0] = row sums of A
    half8 onesb;
    {
        const _Float16 ov = (l15 == 0) ? (_Float16)1.0f : (_Float16)0.0f;
        #pragma unroll
        for (int j = 0; j < 8; ++j) onesb[j] = ov;
    }

    f32x4 o[4];
    f32x4 l16;
    #pragma unroll
    for (int t = 0; t < 4; ++t) { o[t][0]=0.f; o[t][1]=0.f; o[t][2]=0.f; o[t][3]=0.f; }
    l16[0]=0.f; l16[1]=0.f; l16[2]=0.f; l16[3]=0.f;

    // ---- prefetch chunk 0 into registers ----
    uint4 kA, kB, vA;
    float mreg = 0.0f;
    {
        const int k0c = sp * 11 * 64;
        kA = *(const uint4*)(kbase + ((size_t)(k0c +  0 + krow_s) << 7) + kcol_s);
        kB = *(const uint4*)(kbase + ((size_t)(k0c + 32 + krow_s) << 7) + kcol_s);
        vA = *(const uint4*)(vbase + (size_t)(vrow_s) * 1408 + k0c + vcol_s);
        if (tid < 64) {
            const int ki = mko + k0c + tid;
            const int mv = m8 ? (int)mB[ki] : mI[ki];
            mreg = mv ? -1e30f : 0.0f;
        }
    }

    for (int cc = 0; cc < 11; ++cc) {
        // ---- stage prefetched registers to LDS ----
        *(uint4*)&Ks[( 0 + krow_s) * 136 + kcol_s] = kA;
        *(uint4*)&Ks[(32 + krow_s) * 136 + kcol_s] = kB;
        *(uint4*)&Vs[vrow_s * 72 + vcol_s] = vA;
        if (tid < 64) Mb[tid] = mreg;
        __syncthreads();

        // ---- issue next chunk's global loads (in flight under compute) ----
        if (cc < 10) {
            const int k0n = (sp * 11 + cc + 1) * 64;
            kA = *(const uint4*)(kbase + ((size_t)(k0n +  0 + krow_s) << 7) + kcol_s);
            kB = *(const uint4*)(kbase + ((size_t)(k0n + 32 + krow_s) << 7) + kcol_s);
            vA = *(const uint4*)(vbase + (size_t)(vrow_s) * 1408 + k0n + vcol_s);
            if (tid < 64) {
                const int ki = mko + k0n + tid;
                const int mv = m8 ? (int)mB[ki] : mI[ki];
                mreg = mv ? -1e30f : 0.0f;
            }
        }

        // ---- QK^T: accumulator seeded with mask bias ----
        f32x4 s[4];
        #pragma unroll
        for (int t = 0; t < 4; ++t) {
            const float mbv = Mb[t * 16 + l15];
            s[t][0]=mbv; s[t][1]=mbv; s[t][2]=mbv; s[t][3]=mbv;
        }
        #pragma unroll
        for (int k0 = 0; k0 < 4; ++k0)
            #pragma unroll
            for (int t = 0; t < 4; ++t) {
                const half8 kf = *(const half8*)&Ks[(t * 16 + l15) * 136 + k0 * 32 + quad * 8];
                s[t] = __builtin_amdgcn_mfma_f32_16x16x32_f16(qf[k0], kf, s[t], 0, 0, 0);
            }

        // ---- softmax-lite: plain exp, P -> LDS (skewed layout) ----
        #pragma unroll
        for (int r = 0; r < 4; ++r) {
            const float p0 = __expf(s[0][r]);
            const float p1 = __expf(s[1][r]);
            const float p2 = __expf(s[2][r]);
            const float p3 = __expf(s[3][r]);
            u16* pr = &Ps[w][(quad * 4 + r) * 72 + quad * 16 + l15];
            pr[0]  = f2h(p0);
            pr[16] = f2h(p1);
            pr[32] = f2h(p2);
            pr[48] = f2h(p3);
        }

        const u16* prow = &Ps[w][l15 * 72 + (l15 >> 2) * 16 + quad * 8];
        const half8 pa0 = *(const half8*)(prow);
        const half8 pa1 = *(const half8*)(prow + 32);

        // row sums via ones-column MFMA (accumulated across all chunks)
        l16 = __builtin_amdgcn_mfma_f32_16x16x32_f16(pa0, onesb, l16, 0, 0, 0);
        l16 = __builtin_amdgcn_mfma_f32_16x16x32_f16(pa1, onesb, l16, 0, 0, 0);

        #pragma unroll
        for (int t = 0; t < 4; ++t) {
            const half8 v0 = *(const half8*)&Vs[(t * 16 + l15) * 72 + quad * 8];
            const half8 v1 = *(const half8*)&Vs[(t * 16 + l15) * 72 + 32 + quad * 8];
            o[t] = __builtin_amdgcn_mfma_f32_16x16x32_f16(pa0, v0, o[t], 0, 0, 0);
            o[t] = __builtin_amdgcn_mfma_f32_16x16x32_f16(pa1, v1, o[t], 0, 0, 0);
        }
        __syncthreads();
    }

    const int p = sp * 48 + hn_i;
    #pragma unroll
    for (int r = 0; r < 4; ++r) {
        const int gq = q0 + w * 16 + quad * 4 + r;
        if (gq < 900) {
            u16* db = Opart + ((size_t)p * 900 + gq) * 64 + l15;
            db[0]  = f2h(o[0][r]);
            db[16] = f2h(o[1][r]);
            db[32] = f2h(o[2][r]);
            db[48] = f2h(o[3][r]);
            if (l15 == 0) lpart[p * 900 + gq] = l16[r];
        }
    }
}

// =======================================================================================
// Fused epilogue megakernel, 4 rows/block (grid 225), combine fused as prologue.
// (r12 measured-best version.)
// =======================================================================================
__global__ __launch_bounds__(256) void epi_mega(
    const u16* __restrict__ Opart, const float* __restrict__ lpart,
    const u16* __restrict__ T_o,
    const u16* __restrict__ T_m1, const u16* __restrict__ T_m2,
    const float* __restrict__ b_o, const float* __restrict__ q_a,
    const float* __restrict__ ln1_g, const float* __restrict__ ln1_b,
    const float* __restrict__ b_m1, const float* __restrict__ b_m2,
    const float* __restrict__ ln2_g, const float* __restrict__ ln2_b,
    float* __restrict__ outf)
{
    __shared__ u16 A16[4][520];       // 4.2 KB combined attention rows
    __shared__ u16 Z1[16][264];       // 8.4 KB
    __shared__ u16 H[16][520];        // 16.6 KB
    __shared__ float Ssum[4][16];
    __shared__ float Ssq[4][16];

    const int tid = threadIdx.x;
    const int w = tid >> 6, lane = tid & 63;
    const int l15 = lane & 15, quad = lane >> 4;
    const int m0 = blockIdx.x * 4;

    // ================= Prologue: merge 12 partials for this block's 4 rows ============
    {
        const int r = tid >> 6;           // 0..3
        const int cg = tid & 63;          // col-group (8 cols each)
        const int c8 = cg * 8;
        const int hh = cg >> 3;           // head
        const int d8 = c8 & 56;           // d-offset within head
        const int q = m0 + r;             // 900 % 4 == 0 -> always < 900
        float l = 0.f;
        float a0=0.f,a1=0.f,a2=0.f,a3=0.f,a4=0.f,a5=0.f,a6=0.f,a7=0.f;
        #pragma unroll
        for (int s = 0; s < 12; ++s) {
            const int p = ((s & 1) ? 48 : 0) + hh * 6 + (s >> 1);
            l += lpart[p * 900 + q];
            const u16* ob = Opart + ((size_t)p * 900 + q) * 64 + d8;
            const ushort4 t0 = *(const ushort4*)ob;
            const ushort4 t1 = *(const ushort4*)(ob + 4);
            a0 += h2f(t0.x); a1 += h2f(t0.y); a2 += h2f(t0.z); a3 += h2f(t0.w);
            a4 += h2f(t1.x); a5 += h2f(t1.y); a6 += h2f(t1.z); a7 += h2f(t1.w);
        }
        const float inv = 1.0f / fmaxf(l, 1e-30f);
        ushort4 o0, o1;
        o0.x = f2h(a0 * inv); o0.y = f2h(a1 * inv); o0.z = f2h(a2 * inv); o0.w = f2h(a3 * inv);
        o1.x = f2h(a4 * inv); o1.y = f2h(a5 * inv); o1.z = f2h(a6 * inv); o1.w = f2h(a7 * inv);
        *(ushort4*)&A16[r][c8]     = o0;
        *(ushort4*)&A16[r][c8 + 4] = o1;
    }
    __syncthreads();

    // ================= Phase A: out-proj + LN1 =================
    {
        f32x4 acc[4];
        #pragma unroll
        for (int t = 0; t < 4; ++t) { acc[t][0]=0.f; acc[t][1]=0.f; acc[t][2]=0.f; acc[t][3]=0.f; }

        #pragma unroll
        for (int k0 = 0; k0 < 16; ++k0) {
            const half8 af = *(const half8*)&A16[l15 & 3][k0 * 32 + quad * 8];
            #pragma unroll
            for (int t = 0; t < 4; ++t) {
                const int nn = w * 64 + t * 16 + l15;
                const half8 bf = *(const half8*)(T_o + (size_t)nn * 512 + k0 * 32 + quad * 8);
                acc[t] = __builtin_amdgcn_mfma_f32_16x16x32_f16(af, bf, acc[t], 0, 0, 0);
            }
        }

        float vals[4][4];
        #pragma unroll
        for (int r = 0; r < 4; ++r) {
            const int row = m0 + ((quad * 4 + r) & 3);   // valid data only in rows 0..3
            float s = 0.f, sq = 0.f;
            #pragma unroll
            for (int t = 0; t < 4; ++t) {
                const int col = w * 64 + t * 16 + l15;
                const float x = acc[t][r] + b_o[col] + q_a[(size_t)row * 256 + col];
                vals[r][t] = x; s += x; sq += x * x;
            }
            s = sum16(s); sq = sum16(sq);
            if (l15 == 0) { Ssum[w][quad * 4 + r] = s; Ssq[w][quad * 4 + r] = sq; }
        }
        __syncthreads();

        #pragma unroll
        for (int r = 0; r < 4; ++r) {
            const int rl = quad * 4 + r;
            const float st = Ssum[0][rl] + Ssum[1][rl] + Ssum[2][rl] + Ssum[3][rl];
            const float qt = Ssq[0][rl] + Ssq[1][rl] + Ssq[2][rl] + Ssq[3][rl];
            const float mean = st * (1.0f / 256.0f);
            const float var  = qt * (1.0f / 256.0f) - mean * mean;
            const float inv  = rsqrtf(var + 1e-5f);
            #pragma unroll
            for (int t = 0; t < 4; ++t) {
                const int col = w * 64 + t * 16 + l15;
                const float z = (vals[r][t] - mean) * inv * ln1_g[col] + ln1_b[col];
                Z1[rl][col] = f2h(z);
            }
        }
        __syncthreads();
    }

    // ================= Phase B: MLP1 + gelu =================
    {
        f32x4 acc[8];
        #pragma unroll
        for (int t = 0; t < 8; ++t) { acc[t][0]=0.f; acc[t][1]=0.f; acc[t][2]=0.f; acc[t][3]=0.f; }

        #pragma unroll
        for (int k0 = 0; k0 < 8; ++k0) {
            const half8 af = *(const half8*)&Z1[l15][k0 * 32 + quad * 8];
            #pragma unroll
            for (int t = 0; t < 8; ++t) {
                const int nn = w * 128 + t * 16 + l15;
                const half8 bf = *(const half8*)(T_m1 + (size_t)nn * 256 + k0 * 32 + quad * 8);
                acc[t] = __builtin_amdgcn_mfma_f32_16x16x32_f16(af, bf, acc[t], 0, 0, 0);
            }
        }

        #pragma unroll
        for (int r = 0; r < 4; ++r) {
            const int rl = quad * 4 + r;
            #pragma unroll
            for (int t = 0; t < 8; ++t) {
                const int col = w * 128 + t * 16 + l15;
                const float x = acc[t][r] + b_m1[col];
                H[rl][col] = f2h(0.5f * x * (1.0f + erff(x * 0.70710678118654752f)));
            }
        }
        __syncthreads();
    }

    // ================= Phase C: MLP2 + residual + LN2 =================
    {
        f32x4 acc[4];
        #pragma unroll
        for (int t = 0; t < 4; ++t) { acc[t][0]=0.f; acc[t][1]=0.f; acc[t][2]=0.f; acc[t][3]=0.f; }

        #pragma unroll
        for (int k0 = 0; k0 < 16; ++k0) {
            const half8 af = *(const half8*)&H[l15][k0 * 32 + quad * 8];
            #pragma unroll
            for (int t = 0; t < 4; ++t) {
                const int nn = w * 64 + t * 16 + l15;
                const half8 bf = *(const half8*)(T_m2 + (size_t)nn * 512 + k0 * 32 + quad * 8);
                acc[t] = __builtin_amdgcn_mfma_f32_16x16x32_f16(af, bf, acc[t], 0, 0, 0);
            }
        }

        float vals[4][4];
        #pragma unroll
        for (int r = 0; r < 4; ++r) {
            const int rl = quad * 4 + r;
            float s = 0.f, sq = 0.f;
            #pragma unroll
            for (int t = 0; t < 4; ++t) {
                const int col = w * 64 + t * 16 + l15;
                const float x = acc[t][r] + b_m2[col] + h2f(Z1[rl][col]);
                vals[r][t] = x; s += x; sq += x * x;
            }
            s = sum16(s); sq = sum16(sq);
            if (l15 == 0) { Ssum[w][rl] = s; Ssq[w][rl] = sq; }
        }
        __syncthreads();

        #pragma unroll
        for (int r = 0; r < 4; ++r) {
            const int rl = quad * 4 + r;
            const float st = Ssum[0][rl] + Ssum[1][rl] + Ssum[2][rl] + Ssum[3][rl];
            const float qt = Ssq[0][rl] + Ssq[1][rl] + Ssq[2][rl] + Ssq[3][rl];
            const float mean = st * (1.0f / 256.0f);
            const float var  = qt * (1.0f / 256.0f) - mean * mean;
            const float inv  = rsqrtf(var + 1e-5f);
            const int row = m0 + rl;
            if (rl < 4 && row < 900) {
                #pragma unroll
                for (int t = 0; t < 4; ++t) {
                    const int col = w * 64 + t * 16 + l15;
                    outf[(size_t)row * 256 + col] = (vals[r][t] - mean) * inv * ln2_g[col] + ln2_b[col];
                }
            }
        }
    }
}

extern "C" void kernel_launch(void* const* d_in, const int* in_sizes, int n_in,
                              void* d_out, int out_size, void* d_ws, size_t ws_size,
                              hipStream_t stream)
{
    const float* k_g  = (const float*)d_in[0];
    const float* q_g  = (const float*)d_in[1];
    const float* k_a  = (const float*)d_in[2];
    const float* q_a  = (const float*)d_in[3];
    const float* v    = (const float*)d_in[4];
    const void*  mask = d_in[5];
    const float* W_qg = (const float*)d_in[6];
    const float* b_qg = (const float*)d_in[7];
    const float* W_kg = (const float*)d_in[8];
    const float* b_kg = (const float*)d_in[9];
    const float* W_qa = (const float*)d_in[10];
    const float* b_qa = (const float*)d_in[11];
    const float* W_ka = (const float*)d_in[12];
    const float* b_ka = (const float*)d_in[13];
    const float* W_v  = (const float*)d_in[14];
    const float* b_v  = (const float*)d_in[15];
    const float* W_o  = (const float*)d_in[16];
    const float* b_o  = (const float*)d_in[17];
    const float* ln1_g = (const float*)d_in[18];
    const float* ln1_b = (const float*)d_in[19];
    const float* W_m1 = (const float*)d_in[20];
    const float* b_m1 = (const float*)d_in[21];
    const float* W_m2 = (const float*)d_in[22];
    const float* b_m2 = (const float*)d_in[23];
    const float* ln2_g = (const float*)d_in[24];
    const float* ln2_b = (const float*)d_in[25];
    const float* scale_g = (const float*)d_in[26];
    const float* scale_a = (const float*)d_in[27];

    char* ws = (char*)d_ws;
    size_t off = 0;
    auto alloc = [&](size_t bytes) -> void* {
        void* p = ws + off;
        off += (bytes + 255) & ~(size_t)255;
        return p;
    };
    u16*   qcat  = (u16*)  alloc((size_t)8 * 6 * 900  * 128 * 2);
    u16*   kcat  = (u16*)  alloc((size_t)8 * 6 * 1408 * 128 * 2);
    u16*   vt    = (u16*)  alloc((size_t)8 * 6 * 64 * 1408 * 2);
    u16*   Tw[8];
    for (int i = 0; i < 8; ++i) Tw[i] = (u16*)alloc((size_t)512 * 256 * 2);
    float* bkg_s = (float*)alloc((size_t)512 * 4);
    float* bka_s = (float*)alloc((size_t)512 * 4);
    int*   mflag = (int*)  alloc(256);
    u16*   Opart = (u16*)  alloc((size_t)96 * 900 * 64 * 2);
    float* lpart = (float*)alloc((size_t)96 * 900 * 4);

    prep_kernel<<<dim3(8, 8, 9), 256, 0, stream>>>(
        W_qg, W_kg, W_qa, W_ka, W_v, W_o, W_m1, W_m2,
        Tw[0], Tw[1], Tw[2], Tw[3], Tw[4], Tw[5], Tw[6], Tw[7],
        scale_g, scale_a, b_kg, b_ka, bkg_s, bka_s, (const int*)mask, mflag);

    proj_all<<<dim3(496, 2), 256, 0, stream>>>(
        k_g, k_a, v, q_g, q_a,
        Tw[1], Tw[3], Tw[4], Tw[0], Tw[2],
        bkg_s, bka_s, b_v, b_qg, b_qa,
        qcat, kcat, vt);

    attn_kernel<<<768, 512, 0, stream>>>(qcat, kcat, vt, mask, mflag, Opart, lpart);

    epi_mega<<<225, 256, 0, stream>>>(
        Opart, lpart, Tw[5], Tw[6], Tw[7],
        b_o, q_a, ln1_g, ln1_b, b_m1, b_m2, ln2_g, ln2_b,
        (float*)d_out);
}